// Round 4
// baseline (327.285 us; speedup 1.0000x reference)
//
#include <hip/hip_runtime.h>
#include <stdint.h>

// SelfAttentionLayer: x [32,32,32,512] fp32 -> out fp32 same shape
#define B_ 32
#define N_ 1024   // tokens per batch (H*W)
#define C_ 512
#define D_ 64     // DQK

typedef __attribute__((ext_vector_type(8))) __bf16 bf8;   // MFMA A/B frag (4 VGPRs)
typedef __attribute__((ext_vector_type(4))) float f32x4;  // MFMA C/D frag
typedef __attribute__((ext_vector_type(8))) unsigned short u16x8;

typedef const __attribute__((address_space(1))) void* gp_t;
typedef __attribute__((address_space(3))) void* lp_t;

__device__ inline void g2l16(const void* g, void* l) {
    // async global->LDS, 16B/lane; LDS dest = uniform base + lane*16
    __builtin_amdgcn_global_load_lds((gp_t)g, (lp_t)l, 16, 0, 0);
}

__device__ inline float b2f(unsigned short u) {
    return __uint_as_float(((unsigned)u) << 16);
}
__device__ inline unsigned short f2b(float f) {   // f32 -> bf16 bits, RNE
    unsigned u = __float_as_uint(f);
    u += 0x7FFF + ((u >> 16) & 1);
    return (unsigned short)(u >> 16);
}

#define MFMA16(a, b, c) __builtin_amdgcn_mfma_f32_16x16x32_bf16((a), (b), (c), 0, 0, 0)

// ---------------------------------------------------------------------------
// Kernel 0: x fp32 -> bf16 (so qkv can stage via global_load_lds)
// ---------------------------------------------------------------------------
__global__ __launch_bounds__(256) void xcvt(const float* __restrict__ x,
                                            unsigned short* __restrict__ xb) {
    int i = blockIdx.x * 256 + threadIdx.x;      // quad index, exact grid
    float4 f = ((const float4*)x)[i];
    ushort4 o;
    o.x = f2b(f.x); o.y = f2b(f.y); o.z = f2b(f.z); o.w = f2b(f.w);
    ((ushort4*)xb)[i] = o;
}

// ---------------------------------------------------------------------------
// Kernel 0b: weight transpose + cvt into concatenated WT[640][512] bf16.
// ---------------------------------------------------------------------------
__global__ __launch_bounds__(256) void wtrans(const float* __restrict__ w,
                                              unsigned short* __restrict__ wt,
                                              int cout) {
    int t = blockIdx.x * 256 + threadIdx.x;      // output-linear, exact grid
    int co = t >> 9;          // /512
    int ci = t & 511;
    wt[t] = f2b(w[(size_t)ci * cout + co]);
}

// ---------------------------------------------------------------------------
// Kernel 1: QKV projection GEMM. [32768,512]bf16 @ WT[640,512]^T.
// Block tile 128x128, waves 2x2, BK=64, both operands staged fragment-order
// via global_load_lds.  Grid 1D 1280, XCD-swizzled: the 5 col-blocks of one
// row-block run consecutively on ONE XCD -> A tile L2-shared.
// cb 0 -> q|k cols, cb 1..4 -> v cols (v stored transposed vT[b][c][n]).
// ---------------------------------------------------------------------------
__global__ __launch_bounds__(256) void qkv(
    const unsigned short* __restrict__ xb,
    const unsigned short* __restrict__ WT,
    const float* __restrict__ bq, const float* __restrict__ bk,
    const float* __restrict__ bv,
    unsigned short* __restrict__ q, unsigned short* __restrict__ k,
    unsigned short* __restrict__ vT)
{
    const int L = blockIdx.x;          // 0..1279
    const int s = L >> 3;              // 0..159
    const int rb = (L & 7) + 8 * (s / 5);
    const int cb = s % 5;
    const int tid = threadIdx.x;
    const int lane = tid & 63;
    const int wave = tid >> 6;
    const int wm = wave >> 1, wn = wave & 1;
    const int lr = lane & 15;     // frag row/col within 16
    const int lk = lane >> 4;     // k-octet 0..3

    __shared__ unsigned short SM[16896];
    unsigned short* As = SM;                  // [0, 8192)   128x64 frag-order
    unsigned short* Bs = SM + 8192;           // [8192,16384) 128x64 frag-order
    unsigned short* TB = SM;                  // aliased transpose buf 128x132

    const int row0 = rb * 128;
    const int col0 = cb * 128;                // within [640]

    f32x4 zero4 = {0.f, 0.f, 0.f, 0.f};
    f32x4 acc[4][4];
    #pragma unroll
    for (int i = 0; i < 4; ++i)
        #pragma unroll
        for (int j = 0; j < 4; ++j) acc[i][j] = zero4;

    for (int kk = 0; kk < C_; kk += 64) {
        __syncthreads();
        #pragma unroll
        for (int i = 0; i < 4; ++i) {          // 16 frags each for A and B
            int f = wave * 4 + i;
            int t = f >> 1, kq = f & 1;
            g2l16(xb + (size_t)(row0 + t * 16 + lr) * C_ + kk + kq * 32 + lk * 8,
                  &As[f * 512]);
            g2l16(WT + (size_t)(col0 + t * 16 + lr) * C_ + kk + kq * 32 + lk * 8,
                  &Bs[f * 512]);
        }
        __syncthreads();
        #pragma unroll
        for (int kq = 0; kq < 2; ++kq) {
            bf8 a[4], bb[4];
            #pragma unroll
            for (int ti = 0; ti < 4; ++ti)
                a[ti] = *(const bf8*)&As[((wm * 4 + ti) * 2 + kq) * 512 + lane * 8];
            #pragma unroll
            for (int tj = 0; tj < 4; ++tj)
                bb[tj] = *(const bf8*)&Bs[((wn * 4 + tj) * 2 + kq) * 512 + lane * 8];
            #pragma unroll
            for (int ti = 0; ti < 4; ++ti)
                #pragma unroll
                for (int tj = 0; tj < 4; ++tj)
                    acc[ti][tj] = MFMA16(a[ti], bb[tj], acc[ti][tj]);
        }
    }

    if (cb == 0) {
        // wn==0 waves own cols 0..63 (-> q), wn==1 own cols 64..127 (-> k)
        unsigned short* outp = (wn == 0) ? q : k;
        const float* bias = (wn == 0) ? bq : bk;
        #pragma unroll
        for (int ti = 0; ti < 4; ++ti)
            #pragma unroll
            for (int tj = 0; tj < 4; ++tj) {
                int col = tj * 16 + lr;           // 0..63 within q or k
                float bi = bias[col];
                #pragma unroll
                for (int r = 0; r < 4; ++r) {
                    int row = row0 + wm * 64 + ti * 16 + lk * 4 + r;
                    outp[(size_t)row * D_ + col] = f2b(acc[ti][tj][r] + bi);
                }
            }
    } else {
        const int colv = (cb - 1) * 128;          // v col base (0..511)
        __syncthreads();                          // As/Bs reads done; TB aliases
        #pragma unroll
        for (int ti = 0; ti < 4; ++ti)
            #pragma unroll
            for (int tj = 0; tj < 4; ++tj) {
                int c = wn * 64 + tj * 16 + lr;   // 0..127 within block
                float bi = bv[colv + c];
                int tok = wm * 64 + ti * 16 + lk * 4;
                ushort4 o;
                o.x = f2b(acc[ti][tj][0] + bi);
                o.y = f2b(acc[ti][tj][1] + bi);
                o.z = f2b(acc[ti][tj][2] + bi);
                o.w = f2b(acc[ti][tj][3] + bi);
                *(ushort4*)&TB[c * 132 + tok] = o;
            }
        __syncthreads();
        const int b  = row0 >> 10;
        const int n0 = row0 & 1023;
        #pragma unroll
        for (int i = 0; i < 16; ++i) {
            int idx = tid + 256 * i;              // 0..4095
            int c = idx >> 5, ch = idx & 31;
            ushort4 t4 = *(const ushort4*)&TB[c * 132 + ch * 4];
            *(ushort4*)&vT[((size_t)(b * C_ + colv + c)) * N_ + n0 + ch * 4] = t4;
        }
    }
}

// ---------------------------------------------------------------------------
// Kernel 2: FUSED attention: scores + softmax + PV + residual. P never
// touches HBM.  Block = 32 query rows x one batch; grid 1024 (XCD-swizzled
// so a batch's q-strips cluster per XCD -> V L2 reuse).
// Phase 1: S[32][1024] bf16 row-major in LDS via MFMA QK^T.
// Phase 2: per-row softmax (exp stored unnormalized; 1/sum to epilogue).
// Phase 3: O^T = V^T @ P^T: A-frags = vT direct global, B-frags = S rows
//          from LDS (ds_read_b128).  Epilogue: float4 store, *inv + x.
// LDS = 66 KB -> 2 blocks/CU.
// ---------------------------------------------------------------------------
#define SLD 1032   // S leading dim in shorts; 2064B rows: 16B-aligned, bank-spread
__global__ __launch_bounds__(256) void attn(
    const unsigned short* __restrict__ q,
    const unsigned short* __restrict__ k,
    const unsigned short* __restrict__ vT,
    const float* __restrict__ x,
    float* __restrict__ out)
{
    const int bid = blockIdx.x;                 // 0..1023
    const int b   = (bid & 7) + 8 * (bid >> 8); // batch: clusters per XCD
    const int qt  = (bid >> 3) & 31;
    const int n0  = qt * 32;
    const int tid = threadIdx.x, lane = tid & 63, wave = tid >> 6;
    const int lr = lane & 15, lk = lane >> 4;

    __shared__ unsigned short S[32 * SLD];      // 66 KB
    __shared__ float inv_s[32];

    // ---- phase 1: S = (QK^T)*scale, bf16 row-major in LDS ----
    bf8 qa[2][2];
    #pragma unroll
    for (int rt = 0; rt < 2; ++rt)
        #pragma unroll
        for (int kq = 0; kq < 2; ++kq)
            qa[rt][kq] = *(const bf8*)&q[(size_t)(b * N_ + n0 + rt * 16 + lr) * D_
                                         + kq * 32 + lk * 8];

    const int m0w = wave * 256;
    #pragma unroll 2
    for (int mt2 = 0; mt2 < 8; ++mt2) {
        #pragma unroll
        for (int h = 0; h < 2; ++h) {
            int m = m0w + mt2 * 32 + h * 16;
            const unsigned short* kp = k + (size_t)(b * N_ + m + lr) * D_ + lk * 8;
            bf8 kb0 = *(const bf8*)(kp);
            bf8 kb1 = *(const bf8*)(kp + 32);
            #pragma unroll
            for (int rt = 0; rt < 2; ++rt) {
                f32x4 s4 = {0.f, 0.f, 0.f, 0.f};
                s4 = MFMA16(qa[rt][0], kb0, s4);
                s4 = MFMA16(qa[rt][1], kb1, s4);
                #pragma unroll
                for (int r = 0; r < 4; ++r)
                    S[(rt * 16 + lk * 4 + r) * SLD + m + lr] = f2b(s4[r] * 0.125f);
            }
        }
    }
    __syncthreads();

    // ---- phase 2: softmax over each row; store exp, keep 1/sum ----
    #pragma unroll
    for (int i = 0; i < 8; ++i) {
        int row = wave * 8 + i;
        u16x8 a = *(const u16x8*)&S[row * SLD + lane * 16];
        u16x8 c = *(const u16x8*)&S[row * SLD + lane * 16 + 8];
        float v[16];
        #pragma unroll
        for (int j = 0; j < 8; ++j) { v[j] = b2f(a[j]); v[8 + j] = b2f(c[j]); }
        float mx = v[0];
        #pragma unroll
        for (int j = 1; j < 16; ++j) mx = fmaxf(mx, v[j]);
        #pragma unroll
        for (int off = 32; off; off >>= 1) mx = fmaxf(mx, __shfl_xor(mx, off));
        float sum = 0.f;
        #pragma unroll
        for (int j = 0; j < 16; ++j) { v[j] = __expf(v[j] - mx); sum += v[j]; }
        #pragma unroll
        for (int off = 32; off; off >>= 1) sum += __shfl_xor(sum, off);
        u16x8 oa, oc;
        #pragma unroll
        for (int j = 0; j < 8; ++j) { oa[j] = f2b(v[j]); oc[j] = f2b(v[8 + j]); }
        *(u16x8*)&S[row * SLD + lane * 16] = oa;
        *(u16x8*)&S[row * SLD + lane * 16 + 8] = oc;
        if (lane == 0) inv_s[row] = 1.f / sum;
    }
    __syncthreads();

    // ---- phase 3: O^T = V^T @ P^T.  Wave owns 128 channels. ----
    const int cbase = wave * 128;
    f32x4 zero4 = {0.f, 0.f, 0.f, 0.f};
    f32x4 acc[8][2];
    #pragma unroll
    for (int ct = 0; ct < 8; ++ct) { acc[ct][0] = zero4; acc[ct][1] = zero4; }

    const unsigned short* Vb = vT + ((size_t)b * C_ + cbase) * N_;
    #pragma unroll 2
    for (int mt = 0; mt < 32; ++mt) {
        const int m0 = mt * 32;
        bf8 va[8];
        #pragma unroll
        for (int ct = 0; ct < 8; ++ct)
            va[ct] = *(const bf8*)&Vb[(size_t)(ct * 16 + lr) * N_ + m0 + lk * 8];
        bf8 pb0 = *(const bf8*)&S[lr * SLD + m0 + lk * 8];
        bf8 pb1 = *(const bf8*)&S[(16 + lr) * SLD + m0 + lk * 8];
        #pragma unroll
        for (int ct = 0; ct < 8; ++ct) {
            acc[ct][0] = MFMA16(va[ct], pb0, acc[ct][0]);
            acc[ct][1] = MFMA16(va[ct], pb1, acc[ct][1]);
        }
    }

    // ---- epilogue: out = acc*inv + x  (4 consecutive regs = 4 channels) ----
    #pragma unroll
    for (int rt = 0; rt < 2; ++rt) {
        float invr = inv_s[rt * 16 + lr];
        #pragma unroll
        for (int ct = 0; ct < 8; ++ct) {
            size_t base = (size_t)(b * N_ + n0 + rt * 16 + lr) * C_
                        + cbase + ct * 16 + lk * 4;
            float4 xr = *(const float4*)&x[base];
            float4 o;
            o.x = acc[ct][rt][0] * invr + xr.x;
            o.y = acc[ct][rt][1] * invr + xr.y;
            o.z = acc[ct][rt][2] * invr + xr.z;
            o.w = acc[ct][rt][3] * invr + xr.w;
            *(float4*)&out[base] = o;
        }
    }
}

// ---------------------------------------------------------------------------
extern "C" void kernel_launch(void* const* d_in, const int* in_sizes, int n_in,
                              void* d_out, int out_size, void* d_ws, size_t ws_size,
                              hipStream_t stream) {
    (void)in_sizes; (void)n_in; (void)out_size; (void)ws_size;
    const float* xf = (const float*)d_in[0];
    const float* wq = (const float*)d_in[1];
    const float* bq = (const float*)d_in[2];
    const float* wk = (const float*)d_in[3];
    const float* bk = (const float*)d_in[4];
    const float* wv = (const float*)d_in[5];
    const float* bv = (const float*)d_in[6];
    float* out = (float*)d_out;

    // workspace layout (bytes), total ~76 MB (no P buffer anymore):
    //   q [0,4MB) | k [4MB,8MB) | vT [8MB,40MB) | WT (~0.7MB) | xb (32MB)
    char* ws = (char*)d_ws;
    unsigned short* qb  = (unsigned short*)(ws);
    unsigned short* kb  = (unsigned short*)(ws + 4194304);
    unsigned short* vTb = (unsigned short*)(ws + 8388608);
    unsigned short* WT  = (unsigned short*)(ws + 41943040);  // [640][512]
    unsigned short* xb  = (unsigned short*)(ws + 42598400);

    xcvt<<<16384, 256, 0, stream>>>(xf, xb);                 // 16.7M elems
    wtrans<<<128, 256, 0, stream>>>(wq, WT, 64);             // rows 0..63
    wtrans<<<128, 256, 0, stream>>>(wk, WT + 64 * 512, 64);  // rows 64..127
    wtrans<<<1024, 256, 0, stream>>>(wv, WT + 128 * 512, 512); // rows 128..639
    qkv<<<1280, 256, 0, stream>>>(xb, WT, bq, bk, bv, qb, kb, vTb);
    attn<<<1024, 256, 0, stream>>>(qb, kb, vTb, xf, out);
}